// Round 2
// baseline (7115.839 us; speedup 1.0000x reference)
//
#include <hip/hip_runtime.h>
#include <hip/hip_bf16.h>

// Qwen3-Next GatedDeltaNet prefill, B=2, S=2048, HK=16, HV=32, DK=DV=128, K=4.
// Baseline: one workgroup per (batch, value-head); thread v owns state column
// S[:,v] in 128 VGPRs; conv+silu+l2norm computed inline with rolling history.
// All float tensors are fp32 (per reference dtypes); math in fp32.

#define B_    2
#define S_    2048
#define HK_   16
#define HV_   32
#define DK_   128
#define QKV_  8192
#define EPS_  1e-6f

__global__ __launch_bounds__(128)
void gdn_prefill_kernel(const float* __restrict__ xqkv,   // [B*S, QKV]
                        const float* __restrict__ bin,    // [B*S, HV]
                        const float* __restrict__ ain,    // [B*S, HV]
                        const float* __restrict__ wconv,  // [QKV, 4]
                        const float* __restrict__ dtb,    // [HV]
                        const float* __restrict__ alg,    // [HV]
                        float* __restrict__ out)          // [B*S, HV, DV]
{
    const int h   = blockIdx.x;   // value head 0..31
    const int b   = blockIdx.y;   // batch 0..1
    const int hk  = h >> 1;       // GQA: key head = h / (HV/HK)
    const int tid = threadIdx.x;  // 0..127 (column v / channel-within-group)
    const int lane = tid & 63;
    const int wid  = tid >> 6;

    __shared__ __align__(16) float ks[DK_];
    __shared__ __align__(16) float qs[DK_];
    __shared__ float redq[2];
    __shared__ float redk[2];

    // channel index within mixed_qkv row for this thread
    const int qc = hk * DK_ + tid;                  // q block [0, 2048)
    const int kc = HK_ * DK_ + hk * DK_ + tid;      // k block [2048, 4096)
    const int vc = 2 * HK_ * DK_ + h * DK_ + tid;   // v block [4096, 8192)

    // depthwise conv weights for the three channels this thread touches
    float wq[4], wk[4], wv[4];
#pragma unroll
    for (int j = 0; j < 4; ++j) {
        wq[j] = wconv[qc * 4 + j];
        wk[j] = wconv[kc * 4 + j];
        wv[j] = wconv[vc * 4 + j];
    }

    const float neg_exp_alog = -expf(alg[h]);
    const float dt_bias      = dtb[h];
    const float scale        = 0.08838834764831845f;  // 128^-0.5

    // rolling conv history: x[t-3], x[t-2], x[t-1] per channel group
    float hq0 = 0.f, hq1 = 0.f, hq2 = 0.f;
    float hk0 = 0.f, hk1 = 0.f, hk2 = 0.f;
    float hv0 = 0.f, hv1 = 0.f, hv2 = 0.f;

    // state column S[k][v=tid], k = 0..127
    float Sreg[DK_];
#pragma unroll
    for (int k = 0; k < DK_; ++k) Sreg[k] = 0.f;

    const size_t row0 = (size_t)b * S_;

    for (int t = 0; t < S_; ++t) {
        const size_t row = row0 + t;
        const size_t xbase = row * QKV_;

        // ---- load current token channels, conv + silu ----
        const float xq = xqkv[xbase + qc];
        const float xk = xqkv[xbase + kc];
        const float xv = xqkv[xbase + vc];

        float yq = hq0 * wq[0] + hq1 * wq[1] + hq2 * wq[2] + xq * wq[3];
        float yk = hk0 * wk[0] + hk1 * wk[1] + hk2 * wk[2] + xk * wk[3];
        float yv = hv0 * wv[0] + hv1 * wv[1] + hv2 * wv[2] + xv * wv[3];

        hq0 = hq1; hq1 = hq2; hq2 = xq;
        hk0 = hk1; hk1 = hk2; hk2 = xk;
        hv0 = hv1; hv1 = hv2; hv2 = xv;

        yq = yq / (1.f + expf(-yq));   // silu
        yk = yk / (1.f + expf(-yk));
        yv = yv / (1.f + expf(-yv));

        // ---- l2norm sums across 128 channels (2 waves) ----
        float sq = yq * yq;
        float sk = yk * yk;
#pragma unroll
        for (int off = 32; off >= 1; off >>= 1) {
            sq += __shfl_xor(sq, off, 64);
            sk += __shfl_xor(sk, off, 64);
        }
        if (lane == 0) { redq[wid] = sq; redk[wid] = sk; }
        __syncthreads();   // red ready; also: prev iteration's ks/qs fully consumed
        const float sumq = redq[0] + redq[1];
        const float sumk = redk[0] + redk[1];

        const float qn = yq * rsqrtf(sumq + EPS_) * scale;
        const float kn = yk * rsqrtf(sumk + EPS_);
        ks[tid] = kn;
        qs[tid] = qn;

        // ---- gating scalars (uniform per block; computed redundantly) ----
        const size_t rab = row * HV_ + h;
        const float aval = ain[rab] + dt_bias;
        const float sp   = (aval > 20.f) ? aval : log1pf(expf(aval));  // softplus
        const float eg   = expf(neg_exp_alog * sp);                    // exp(g) in (0,1]
        const float beta = 1.f / (1.f + expf(-bin[rab]));

        __syncthreads();   // ks/qs visible

        // ---- pass 1: decay + pred = sum_k k[k] * (S[k][v] * eg) ----
        float pred = 0.f;
#pragma unroll
        for (int k4 = 0; k4 < DK_ / 4; ++k4) {
            const float4 kv = *reinterpret_cast<const float4*>(&ks[k4 * 4]);
            float s;
            s = Sreg[4 * k4 + 0] * eg; Sreg[4 * k4 + 0] = s; pred += kv.x * s;
            s = Sreg[4 * k4 + 1] * eg; Sreg[4 * k4 + 1] = s; pred += kv.y * s;
            s = Sreg[4 * k4 + 2] * eg; Sreg[4 * k4 + 2] = s; pred += kv.z * s;
            s = Sreg[4 * k4 + 3] * eg; Sreg[4 * k4 + 3] = s; pred += kv.w * s;
        }

        const float delta = beta * (yv - pred);

        // ---- pass 2: rank-1 update + output dot ----
        float o = 0.f;
#pragma unroll
        for (int k4 = 0; k4 < DK_ / 4; ++k4) {
            const float4 kv = *reinterpret_cast<const float4*>(&ks[k4 * 4]);
            const float4 qv = *reinterpret_cast<const float4*>(&qs[k4 * 4]);
            float s;
            s = Sreg[4 * k4 + 0] + kv.x * delta; Sreg[4 * k4 + 0] = s; o += qv.x * s;
            s = Sreg[4 * k4 + 1] + kv.y * delta; Sreg[4 * k4 + 1] = s; o += qv.y * s;
            s = Sreg[4 * k4 + 2] + kv.z * delta; Sreg[4 * k4 + 2] = s; o += qv.z * s;
            s = Sreg[4 * k4 + 3] + kv.w * delta; Sreg[4 * k4 + 3] = s; o += qv.w * s;
        }

        out[rab * DK_ + tid] = o;
    }
}

extern "C" void kernel_launch(void* const* d_in, const int* in_sizes, int n_in,
                              void* d_out, int out_size, void* d_ws, size_t ws_size,
                              hipStream_t stream) {
    const float* xqkv  = (const float*)d_in[0];
    const float* bin   = (const float*)d_in[1];
    const float* ain   = (const float*)d_in[2];
    const float* wconv = (const float*)d_in[3];
    const float* dtb   = (const float*)d_in[4];
    const float* alg   = (const float*)d_in[5];
    float* out = (float*)d_out;

    dim3 grid(HV_, B_);
    dim3 block(128);
    gdn_prefill_kernel<<<grid, block, 0, stream>>>(xqkv, bin, ain, wconv, dtb, alg, out);
}

// Round 3
// 2454.460 us; speedup vs baseline: 2.8991x; 2.8991x over previous
//
#include <hip/hip_runtime.h>
#include <hip/hip_bf16.h>

// Qwen3-Next GatedDeltaNet prefill, B=2, S=2048, HK=16, HV=32, DK=DV=128, K=4.
// Round 3: split into (a) parallel preprocess (conv+silu+l2norm -> Y workspace),
// (b) parallel gating (exp(g), beta), (c) serial recurrence with 256 blocks
// (4 v-slices per head), quad-split k-dim, DPP shuffle reductions, reg prefetch.

#define B_    2
#define S_    2048
#define HK_   16
#define HV_   32
#define DK_   128
#define QKV_  8192
#define EPS_  1e-6f
#define SCALE_ 0.08838834764831845f   // 128^-0.5

// ---------------------------------------------------------------------------
// Preprocess: y = silu(causal_conv(x)); q/k parts l2-normalized per 128-ch head
// (q also pre-scaled by DK^-0.5). Y layout identical to x: [B*S, 8192].
// grid (4 segs of 2048 ch, B*S rows), block 256, 8 channels/thread.
// ---------------------------------------------------------------------------
__global__ __launch_bounds__(256)
void preproc_kernel(const float* __restrict__ x, const float* __restrict__ w,
                    float* __restrict__ Y)
{
    const int seg = blockIdx.x;          // 0:q 1:k 2,3:v
    const int bt  = blockIdx.y;          // 0..B*S-1
    const int t   = bt & (S_ - 1);       // token within sequence
    const int tid = threadIdx.x;
    const int c0  = seg * 2048 + tid * 8;

    float4 w4[8];
#pragma unroll
    for (int i = 0; i < 8; ++i)
        w4[i] = *reinterpret_cast<const float4*>(&w[(c0 + i) * 4]);

    float y[8];
#pragma unroll
    for (int i = 0; i < 8; ++i) y[i] = 0.f;

#pragma unroll
    for (int j = 0; j < 4; ++j) {
        const int r = t - 3 + j;
        if (r >= 0) {
            const float* xr = &x[(size_t)(bt - (3 - j)) * QKV_ + c0];
            const float4 a0 = *reinterpret_cast<const float4*>(xr);
            const float4 a1 = *reinterpret_cast<const float4*>(xr + 4);
            const float xv[8] = {a0.x, a0.y, a0.z, a0.w, a1.x, a1.y, a1.z, a1.w};
#pragma unroll
            for (int i = 0; i < 8; ++i)
                y[i] += xv[i] * (&w4[i].x)[j];
        }
    }
#pragma unroll
    for (int i = 0; i < 8; ++i)
        y[i] = y[i] / (1.f + expf(-y[i]));     // silu

    if (seg < 2) {                              // l2norm per 128-ch head (16 lanes)
        float s = 0.f;
#pragma unroll
        for (int i = 0; i < 8; ++i) s += y[i] * y[i];
#pragma unroll
        for (int off = 8; off >= 1; off >>= 1)
            s += __shfl_xor(s, off, 64);        // sums within 16-lane group
        float rn = rsqrtf(s + EPS_);
        if (seg == 0) rn *= SCALE_;
#pragma unroll
        for (int i = 0; i < 8; ++i) y[i] *= rn;
    }

    float4* dst = reinterpret_cast<float4*>(&Y[(size_t)bt * QKV_ + c0]);
    dst[0] = make_float4(y[0], y[1], y[2], y[3]);
    dst[1] = make_float4(y[4], y[5], y[6], y[7]);
}

// ---------------------------------------------------------------------------
// Gating: EG = exp(-exp(alog)*softplus(a+dt_bias)), BT = sigmoid(b). [B*S,HV]
// ---------------------------------------------------------------------------
__global__ __launch_bounds__(256)
void gating_kernel(const float* __restrict__ bin, const float* __restrict__ ain,
                   const float* __restrict__ dtb, const float* __restrict__ alg,
                   float* __restrict__ EG, float* __restrict__ BT)
{
    const int i = blockIdx.x * 256 + threadIdx.x;
    if (i >= B_ * S_ * HV_) return;
    const int h = i & (HV_ - 1);
    const float av = ain[i] + dtb[h];
    const float sp = (av > 20.f) ? av : log1pf(expf(av));
    EG[i] = expf(-expf(alg[h]) * sp);
    BT[i] = 1.f / (1.f + expf(-bin[i]));
}

// ---------------------------------------------------------------------------
// Recurrence: grid (HV, B, 4 v-slices) = 256 blocks, 128 threads.
// thread = (vcol = vs*32 + tid>>2, kh = tid&3); owns S[kh*32 .. +31][vcol].
// No LDS, no barriers; quad reductions via DPP shuffles; 1-token reg prefetch.
// ---------------------------------------------------------------------------
__global__ __launch_bounds__(128, 1)
void recur_kernel(const float* __restrict__ Y, const float* __restrict__ EG,
                  const float* __restrict__ BT, float* __restrict__ out)
{
    const int h    = blockIdx.x;
    const int b    = blockIdx.y;
    const int vs   = blockIdx.z;
    const int hk   = h >> 1;
    const int tid  = threadIdx.x;
    const int kh   = tid & 3;
    const int vcol = vs * 32 + (tid >> 2);

    const size_t qoff = (size_t)hk * DK_ + kh * 32;          // q frag in row
    const size_t koff = 2048 + qoff;                          // k frag in row
    const size_t voff = 4096 + (size_t)h * DK_ + vcol;        // v elem in row

    float S[32];
#pragma unroll
    for (int j = 0; j < 32; ++j) S[j] = 0.f;

    float kf[32], qf[32], vv, eg, bt;
    {
        const float* row = Y + (size_t)(b * S_) * QKV_;
#pragma unroll
        for (int j4 = 0; j4 < 8; ++j4) {
            const float4 kq = *reinterpret_cast<const float4*>(row + koff + j4 * 4);
            const float4 qq = *reinterpret_cast<const float4*>(row + qoff + j4 * 4);
            kf[4*j4+0] = kq.x; kf[4*j4+1] = kq.y; kf[4*j4+2] = kq.z; kf[4*j4+3] = kq.w;
            qf[4*j4+0] = qq.x; qf[4*j4+1] = qq.y; qf[4*j4+2] = qq.z; qf[4*j4+3] = qq.w;
        }
        vv = row[voff];
        eg = EG[(size_t)(b * S_) * HV_ + h];
        bt = BT[(size_t)(b * S_) * HV_ + h];
    }

    for (int t = 0; t < S_; ++t) {
        // ---- issue prefetch of token t+1 (clamped) ----
        const int tn = (t + 1 < S_) ? (t + 1) : t;
        const float* rowp = Y + (size_t)(b * S_ + tn) * QKV_;
        float kn[32], qn[32];
#pragma unroll
        for (int j4 = 0; j4 < 8; ++j4) {
            const float4 kq = *reinterpret_cast<const float4*>(rowp + koff + j4 * 4);
            const float4 qq = *reinterpret_cast<const float4*>(rowp + qoff + j4 * 4);
            kn[4*j4+0] = kq.x; kn[4*j4+1] = kq.y; kn[4*j4+2] = kq.z; kn[4*j4+3] = kq.w;
            qn[4*j4+0] = qq.x; qn[4*j4+1] = qq.y; qn[4*j4+2] = qq.z; qn[4*j4+3] = qq.w;
        }
        const float vn  = rowp[voff];
        const float egn = EG[(size_t)(b * S_ + tn) * HV_ + h];
        const float btn = BT[(size_t)(b * S_ + tn) * HV_ + h];

        // ---- pass 1: decay + partial pred over this thread's 32 k's ----
        float p0 = 0.f, p1 = 0.f, p2 = 0.f, p3 = 0.f;
#pragma unroll
        for (int j = 0; j < 32; j += 4) {
            float s0 = S[j+0] * eg; S[j+0] = s0; p0 += kf[j+0] * s0;
            float s1 = S[j+1] * eg; S[j+1] = s1; p1 += kf[j+1] * s1;
            float s2 = S[j+2] * eg; S[j+2] = s2; p2 += kf[j+2] * s2;
            float s3 = S[j+3] * eg; S[j+3] = s3; p3 += kf[j+3] * s3;
        }
        float pred = (p0 + p1) + (p2 + p3);
        pred += __shfl_xor(pred, 1, 64);       // DPP quad reductions
        pred += __shfl_xor(pred, 2, 64);
        const float delta = bt * (vv - pred);

        // ---- pass 2: rank-1 update + partial output dot ----
        float o0 = 0.f, o1 = 0.f, o2 = 0.f, o3 = 0.f;
#pragma unroll
        for (int j = 0; j < 32; j += 4) {
            float s0 = S[j+0] + kf[j+0] * delta; S[j+0] = s0; o0 += qf[j+0] * s0;
            float s1 = S[j+1] + kf[j+1] * delta; S[j+1] = s1; o1 += qf[j+1] * s1;
            float s2 = S[j+2] + kf[j+2] * delta; S[j+2] = s2; o2 += qf[j+2] * s2;
            float s3 = S[j+3] + kf[j+3] * delta; S[j+3] = s3; o3 += qf[j+3] * s3;
        }
        float o = (o0 + o1) + (o2 + o3);
        o += __shfl_xor(o, 1, 64);
        o += __shfl_xor(o, 2, 64);
        if (kh == 0)
            out[((size_t)(b * S_ + t) * HV_ + h) * DK_ + vcol] = o;

        // ---- rotate prefetch regs ----
#pragma unroll
        for (int j = 0; j < 32; ++j) { kf[j] = kn[j]; qf[j] = qn[j]; }
        vv = vn; eg = egn; bt = btn;
    }
}

// ---------------------------------------------------------------------------
// Fallback (round-2 monolithic kernel) if workspace is too small.
// ---------------------------------------------------------------------------
__global__ __launch_bounds__(128)
void gdn_prefill_fallback(const float* __restrict__ xqkv, const float* __restrict__ bin,
                          const float* __restrict__ ain, const float* __restrict__ wconv,
                          const float* __restrict__ dtb, const float* __restrict__ alg,
                          float* __restrict__ out)
{
    const int h = blockIdx.x, b = blockIdx.y;
    const int hk = h >> 1;
    const int tid = threadIdx.x, lane = tid & 63, wid = tid >> 6;
    __shared__ __align__(16) float ks[DK_];
    __shared__ __align__(16) float qs[DK_];
    __shared__ float redq[2], redk[2];
    const int qc = hk * DK_ + tid, kc = HK_ * DK_ + hk * DK_ + tid,
              vc = 2 * HK_ * DK_ + h * DK_ + tid;
    float wq[4], wk[4], wv[4];
#pragma unroll
    for (int j = 0; j < 4; ++j) {
        wq[j] = wconv[qc*4+j]; wk[j] = wconv[kc*4+j]; wv[j] = wconv[vc*4+j];
    }
    const float nea = -expf(alg[h]), dbi = dtb[h];
    float hq0=0,hq1=0,hq2=0,hk0=0,hk1=0,hk2=0,hv0=0,hv1=0,hv2=0;
    float Sr[DK_];
#pragma unroll
    for (int k = 0; k < DK_; ++k) Sr[k] = 0.f;
    const size_t row0 = (size_t)b * S_;
    for (int t = 0; t < S_; ++t) {
        const size_t row = row0 + t, xb = row * QKV_;
        const float xq = xqkv[xb+qc], xk = xqkv[xb+kc], xv = xqkv[xb+vc];
        float yq = hq0*wq[0]+hq1*wq[1]+hq2*wq[2]+xq*wq[3];
        float yk = hk0*wk[0]+hk1*wk[1]+hk2*wk[2]+xk*wk[3];
        float yv = hv0*wv[0]+hv1*wv[1]+hv2*wv[2]+xv*wv[3];
        hq0=hq1;hq1=hq2;hq2=xq; hk0=hk1;hk1=hk2;hk2=xk; hv0=hv1;hv1=hv2;hv2=xv;
        yq = yq/(1.f+expf(-yq)); yk = yk/(1.f+expf(-yk)); yv = yv/(1.f+expf(-yv));
        float sq = yq*yq, sk = yk*yk;
#pragma unroll
        for (int off = 32; off >= 1; off >>= 1) {
            sq += __shfl_xor(sq, off, 64); sk += __shfl_xor(sk, off, 64);
        }
        if (lane == 0) { redq[wid] = sq; redk[wid] = sk; }
        __syncthreads();
        const float qn = yq * rsqrtf(redq[0]+redq[1]+EPS_) * SCALE_;
        const float kn = yk * rsqrtf(redk[0]+redk[1]+EPS_);
        ks[tid] = kn; qs[tid] = qn;
        const size_t rab = row * HV_ + h;
        const float av = ain[rab] + dbi;
        const float sp = (av > 20.f) ? av : log1pf(expf(av));
        const float eg = expf(nea * sp);
        const float beta = 1.f/(1.f+expf(-bin[rab]));
        __syncthreads();
        float pred = 0.f;
#pragma unroll
        for (int k4 = 0; k4 < DK_/4; ++k4) {
            const float4 kv = *reinterpret_cast<const float4*>(&ks[k4*4]);
            float s;
            s = Sr[4*k4+0]*eg; Sr[4*k4+0]=s; pred += kv.x*s;
            s = Sr[4*k4+1]*eg; Sr[4*k4+1]=s; pred += kv.y*s;
            s = Sr[4*k4+2]*eg; Sr[4*k4+2]=s; pred += kv.z*s;
            s = Sr[4*k4+3]*eg; Sr[4*k4+3]=s; pred += kv.w*s;
        }
        const float delta = beta * (yv - pred);
        float o = 0.f;
#pragma unroll
        for (int k4 = 0; k4 < DK_/4; ++k4) {
            const float4 kv = *reinterpret_cast<const float4*>(&ks[k4*4]);
            const float4 qv = *reinterpret_cast<const float4*>(&qs[k4*4]);
            float s;
            s = Sr[4*k4+0]+kv.x*delta; Sr[4*k4+0]=s; o += qv.x*s;
            s = Sr[4*k4+1]+kv.y*delta; Sr[4*k4+1]=s; o += qv.y*s;
            s = Sr[4*k4+2]+kv.z*delta; Sr[4*k4+2]=s; o += qv.z*s;
            s = Sr[4*k4+3]+kv.w*delta; Sr[4*k4+3]=s; o += qv.w*s;
        }
        out[rab * DK_ + tid] = o;
    }
}

extern "C" void kernel_launch(void* const* d_in, const int* in_sizes, int n_in,
                              void* d_out, int out_size, void* d_ws, size_t ws_size,
                              hipStream_t stream) {
    const float* xqkv  = (const float*)d_in[0];
    const float* bin   = (const float*)d_in[1];
    const float* ain   = (const float*)d_in[2];
    const float* wconv = (const float*)d_in[3];
    const float* dtb   = (const float*)d_in[4];
    const float* alg   = (const float*)d_in[5];
    float* out = (float*)d_out;

    const size_t Y_BYTES  = (size_t)B_ * S_ * QKV_ * 4;   // 134 MB
    const size_t G_BYTES  = (size_t)B_ * S_ * HV_ * 4;    // 0.5 MB
    const size_t NEEDED   = Y_BYTES + 2 * G_BYTES;

    if (ws_size >= NEEDED) {
        float* Y  = (float*)d_ws;
        float* EG = (float*)((char*)d_ws + Y_BYTES);
        float* BT = (float*)((char*)d_ws + Y_BYTES + G_BYTES);

        preproc_kernel<<<dim3(4, B_ * S_), 256, 0, stream>>>(xqkv, wconv, Y);
        gating_kernel<<<dim3((B_ * S_ * HV_ + 255) / 256), 256, 0, stream>>>(
            bin, ain, dtb, alg, EG, BT);
        recur_kernel<<<dim3(HV_, B_, 4), 128, 0, stream>>>(Y, EG, BT, out);
    } else {
        gdn_prefill_fallback<<<dim3(HV_, B_), 128, 0, stream>>>(
            xqkv, bin, ain, wconv, dtb, alg, out);
    }
}

// Round 4
// 1666.582 us; speedup vs baseline: 4.2697x; 1.4728x over previous
//
#include <hip/hip_runtime.h>
#include <hip/hip_bf16.h>

// Qwen3-Next GatedDeltaNet prefill, B=2, S=2048, HK=16, HV=32, DK=DV=128, K=4.
// Round 4: recurrence restructured for latency:
//  - 1024 single-wave blocks (HV x B x 16 v-slices), 1 wave on every SIMD
//  - thread = (vcol in 8, kh in 8 groups of 16 k); S[16] per thread
//  - manual 2x unrolled A/B register double-buffer (no rotation copies, so the
//    compiler cannot coalesce+sink the prefetch), sched_barrier(0) pinning
//  - cross-kh reductions via 3 shfl_xor (DPP), no LDS, no barriers
// Preproc: 4 tokens/block with rolling conv history; gating packs (eg, beta).

#define B_    2
#define S_    2048
#define HK_   16
#define HV_   32
#define DK_   128
#define QKV_  8192
#define EPS_  1e-6f
#define SCALE_ 0.08838834764831845f   // 128^-0.5

// ---------------------------------------------------------------------------
// Preprocess: y = silu(causal_conv(x)); q/k l2-normalized per 128-ch head,
// q pre-scaled by DK^-0.5. Y layout = x layout: [B*S, 8192].
// grid (4 segs, B*S/4), block 256, 8 ch/thread, 4 tokens/block (rolling hist).
// ---------------------------------------------------------------------------
__global__ __launch_bounds__(256)
void preproc_kernel(const float* __restrict__ x, const float* __restrict__ w,
                    float* __restrict__ Y)
{
    const int seg = blockIdx.x;            // 0:q 1:k 2,3:v
    const int bt0 = blockIdx.y * 4;        // first global row of this block
    const int t0  = bt0 & (S_ - 1);        // token within sequence
    const int tid = threadIdx.x;
    const int c0  = seg * 2048 + tid * 8;

    float4 w4[8];
#pragma unroll
    for (int i = 0; i < 8; ++i)
        w4[i] = *reinterpret_cast<const float4*>(&w[(c0 + i) * 4]);

    float h0[8], h1[8], h2[8], cur[8], y[8];

    // rolling history rows t0-3, t0-2, t0-1 (zero before sequence start)
#pragma unroll
    for (int i = 0; i < 8; ++i) { h0[i] = 0.f; h1[i] = 0.f; h2[i] = 0.f; }
    if (t0 >= 3) {   // t0 is a multiple of 4, so either 0 (all zero) or >=4
        const float* r0 = &x[(size_t)(bt0 - 3) * QKV_ + c0];
        const float* r1 = &x[(size_t)(bt0 - 2) * QKV_ + c0];
        const float* r2 = &x[(size_t)(bt0 - 1) * QKV_ + c0];
#pragma unroll
        for (int i4 = 0; i4 < 2; ++i4) {
            const float4 a = *reinterpret_cast<const float4*>(r0 + i4 * 4);
            const float4 b = *reinterpret_cast<const float4*>(r1 + i4 * 4);
            const float4 c = *reinterpret_cast<const float4*>(r2 + i4 * 4);
            h0[4*i4+0]=a.x; h0[4*i4+1]=a.y; h0[4*i4+2]=a.z; h0[4*i4+3]=a.w;
            h1[4*i4+0]=b.x; h1[4*i4+1]=b.y; h1[4*i4+2]=b.z; h1[4*i4+3]=b.w;
            h2[4*i4+0]=c.x; h2[4*i4+1]=c.y; h2[4*i4+2]=c.z; h2[4*i4+3]=c.w;
        }
    }

#pragma unroll
    for (int tt = 0; tt < 4; ++tt) {
        const float* rc = &x[(size_t)(bt0 + tt) * QKV_ + c0];
#pragma unroll
        for (int i4 = 0; i4 < 2; ++i4) {
            const float4 a = *reinterpret_cast<const float4*>(rc + i4 * 4);
            cur[4*i4+0]=a.x; cur[4*i4+1]=a.y; cur[4*i4+2]=a.z; cur[4*i4+3]=a.w;
        }
#pragma unroll
        for (int i = 0; i < 8; ++i) {
            float v = h0[i]*w4[i].x + h1[i]*w4[i].y + h2[i]*w4[i].z + cur[i]*w4[i].w;
            y[i] = v / (1.f + expf(-v));                 // silu
        }
        if (seg < 2) {                                    // l2norm over 128 ch = 16 lanes
            float s = 0.f;
#pragma unroll
            for (int i = 0; i < 8; ++i) s += y[i] * y[i];
#pragma unroll
            for (int off = 8; off >= 1; off >>= 1)
                s += __shfl_xor(s, off, 64);
            float rn = rsqrtf(s + EPS_);
            if (seg == 0) rn *= SCALE_;
#pragma unroll
            for (int i = 0; i < 8; ++i) y[i] *= rn;
        }
        float4* dst = reinterpret_cast<float4*>(&Y[(size_t)(bt0 + tt) * QKV_ + c0]);
        dst[0] = make_float4(y[0], y[1], y[2], y[3]);
        dst[1] = make_float4(y[4], y[5], y[6], y[7]);
        // roll history
#pragma unroll
        for (int i = 0; i < 8; ++i) { h0[i] = h1[i]; h1[i] = h2[i]; h2[i] = cur[i]; }
    }
}

// ---------------------------------------------------------------------------
// Gating: GB[i] = (exp(-exp(alog)*softplus(a+dt_bias)), sigmoid(b)). [B*S,HV]
// ---------------------------------------------------------------------------
__global__ __launch_bounds__(256)
void gating_kernel(const float* __restrict__ bin, const float* __restrict__ ain,
                   const float* __restrict__ dtb, const float* __restrict__ alg,
                   float2* __restrict__ GB)
{
    const int i = blockIdx.x * 256 + threadIdx.x;
    if (i >= B_ * S_ * HV_) return;
    const int h = i & (HV_ - 1);
    const float av = ain[i] + dtb[h];
    const float sp = (av > 20.f) ? av : log1pf(expf(av));
    GB[i] = make_float2(expf(-expf(alg[h]) * sp), 1.f / (1.f + expf(-bin[i])));
}

// ---------------------------------------------------------------------------
// Recurrence helpers
// ---------------------------------------------------------------------------
__device__ __forceinline__ void load_tok(const float* __restrict__ row,
                                         int koff, int qoff, int voff,
                                         float (&kf)[16], float (&qf)[16], float& vv)
{
#pragma unroll
    for (int j4 = 0; j4 < 4; ++j4) {
        const float4 kq = *reinterpret_cast<const float4*>(row + koff + j4 * 4);
        const float4 qq = *reinterpret_cast<const float4*>(row + qoff + j4 * 4);
        kf[4*j4+0]=kq.x; kf[4*j4+1]=kq.y; kf[4*j4+2]=kq.z; kf[4*j4+3]=kq.w;
        qf[4*j4+0]=qq.x; qf[4*j4+1]=qq.y; qf[4*j4+2]=qq.z; qf[4*j4+3]=qq.w;
    }
    vv = row[voff];
}

__device__ __forceinline__ void step_tok(float (&S)[16],
                                         const float (&kf)[16], const float (&qf)[16],
                                         float vv, float2 g, int kh,
                                         float* __restrict__ optr)
{
    const float eg = g.x, bt = g.y;
    float p0 = 0.f, p1 = 0.f, p2 = 0.f, p3 = 0.f;
#pragma unroll
    for (int j = 0; j < 16; j += 4) {
        float s0 = S[j+0] * eg; S[j+0] = s0; p0 += kf[j+0] * s0;
        float s1 = S[j+1] * eg; S[j+1] = s1; p1 += kf[j+1] * s1;
        float s2 = S[j+2] * eg; S[j+2] = s2; p2 += kf[j+2] * s2;
        float s3 = S[j+3] * eg; S[j+3] = s3; p3 += kf[j+3] * s3;
    }
    float pred = (p0 + p1) + (p2 + p3);
    pred += __shfl_xor(pred, 1, 64);
    pred += __shfl_xor(pred, 2, 64);
    pred += __shfl_xor(pred, 4, 64);
    const float delta = bt * (vv - pred);

    float o0 = 0.f, o1 = 0.f, o2 = 0.f, o3 = 0.f;
#pragma unroll
    for (int j = 0; j < 16; j += 4) {
        float s0 = S[j+0] + kf[j+0] * delta; S[j+0] = s0; o0 += qf[j+0] * s0;
        float s1 = S[j+1] + kf[j+1] * delta; S[j+1] = s1; o1 += qf[j+1] * s1;
        float s2 = S[j+2] + kf[j+2] * delta; S[j+2] = s2; o2 += qf[j+2] * s2;
        float s3 = S[j+3] + kf[j+3] * delta; S[j+3] = s3; o3 += qf[j+3] * s3;
    }
    float o = (o0 + o1) + (o2 + o3);
    o += __shfl_xor(o, 1, 64);
    o += __shfl_xor(o, 2, 64);
    o += __shfl_xor(o, 4, 64);
    if (kh == 0) *optr = o;
}

// ---------------------------------------------------------------------------
// Recurrence: grid (HV, B, 16 v-slices) = 1024 single-wave blocks, 64 threads.
// thread = (vcol = vs*8 + lane>>3, kh = lane&7); owns S[kh*16 .. +15][vcol].
// ---------------------------------------------------------------------------
__global__ __launch_bounds__(64, 1)
void recur_kernel(const float* __restrict__ Y, const float2* __restrict__ GB,
                  float* __restrict__ out)
{
    const int h    = blockIdx.x;
    const int b    = blockIdx.y;
    const int vs   = blockIdx.z;
    const int hk   = h >> 1;
    const int lane = threadIdx.x;
    const int kh   = lane & 7;
    const int vcol = vs * 8 + (lane >> 3);

    const int qoff = hk * DK_ + kh * 16;
    const int koff = 2048 + qoff;
    const int voff = 4096 + h * DK_ + vcol;

    float S[16];
#pragma unroll
    for (int j = 0; j < 16; ++j) S[j] = 0.f;

    const float*  rowBase = Y + (size_t)(b * S_) * QKV_;
    const float2* gbase   = GB + (size_t)(b * S_) * HV_ + h;
    float* obase = out + ((size_t)(b * S_) * HV_ + h) * (size_t)DK_ + vcol;

    float kA[16], qA[16], vA, kB[16], qB[16], vB;
    float2 gA, gB2;

    load_tok(rowBase,        koff, qoff, voff, kA, qA, vA); gA  = gbase[0];
    load_tok(rowBase + QKV_, koff, qoff, voff, kB, qB, vB); gB2 = gbase[HV_];

    for (int t = 0; t < S_; t += 2) {
        // token t from buffer A
        step_tok(S, kA, qA, vA, gA, kh, obase + (size_t)t * (HV_ * DK_));
        // refill A with token t+2 (clamped; extra loads at the tail are unused)
        {
            const int ta = (t + 2 < S_) ? (t + 2) : (S_ - 1);
            load_tok(rowBase + (size_t)ta * QKV_, koff, qoff, voff, kA, qA, vA);
            gA = gbase[(size_t)ta * HV_];
        }
        __builtin_amdgcn_sched_barrier(0);   // pin refill-A ahead of step-B
        // token t+1 from buffer B
        step_tok(S, kB, qB, vB, gB2, kh, obase + (size_t)(t + 1) * (HV_ * DK_));
        // refill B with token t+3
        {
            const int tb = (t + 3 < S_) ? (t + 3) : (S_ - 1);
            load_tok(rowBase + (size_t)tb * QKV_, koff, qoff, voff, kB, qB, vB);
            gB2 = gbase[(size_t)tb * HV_];
        }
    }
}

// ---------------------------------------------------------------------------
// Fallback (round-2 monolithic kernel) if workspace is too small.
// ---------------------------------------------------------------------------
__global__ __launch_bounds__(128)
void gdn_prefill_fallback(const float* __restrict__ xqkv, const float* __restrict__ bin,
                          const float* __restrict__ ain, const float* __restrict__ wconv,
                          const float* __restrict__ dtb, const float* __restrict__ alg,
                          float* __restrict__ out)
{
    const int h = blockIdx.x, b = blockIdx.y;
    const int hk = h >> 1;
    const int tid = threadIdx.x, lane = tid & 63, wid = tid >> 6;
    __shared__ __align__(16) float ks[DK_];
    __shared__ __align__(16) float qs[DK_];
    __shared__ float redq[2], redk[2];
    const int qc = hk * DK_ + tid, kc = HK_ * DK_ + hk * DK_ + tid,
              vc = 2 * HK_ * DK_ + h * DK_ + tid;
    float wq[4], wk[4], wv[4];
#pragma unroll
    for (int j = 0; j < 4; ++j) {
        wq[j] = wconv[qc*4+j]; wk[j] = wconv[kc*4+j]; wv[j] = wconv[vc*4+j];
    }
    const float nea = -expf(alg[h]), dbi = dtb[h];
    float hq0=0,hq1=0,hq2=0,hk0=0,hk1=0,hk2=0,hv0=0,hv1=0,hv2=0;
    float Sr[DK_];
#pragma unroll
    for (int k = 0; k < DK_; ++k) Sr[k] = 0.f;
    const size_t row0 = (size_t)b * S_;
    for (int t = 0; t < S_; ++t) {
        const size_t row = row0 + t, xb = row * QKV_;
        const float xq = xqkv[xb+qc], xk = xqkv[xb+kc], xv = xqkv[xb+vc];
        float yq = hq0*wq[0]+hq1*wq[1]+hq2*wq[2]+xq*wq[3];
        float yk = hk0*wk[0]+hk1*wk[1]+hk2*wk[2]+xk*wk[3];
        float yv = hv0*wv[0]+hv1*wv[1]+hv2*wv[2]+xv*wv[3];
        hq0=hq1;hq1=hq2;hq2=xq; hk0=hk1;hk1=hk2;hk2=xk; hv0=hv1;hv1=hv2;hv2=xv;
        yq = yq/(1.f+expf(-yq)); yk = yk/(1.f+expf(-yk)); yv = yv/(1.f+expf(-yv));
        float sq = yq*yq, sk = yk*yk;
#pragma unroll
        for (int off = 32; off >= 1; off >>= 1) {
            sq += __shfl_xor(sq, off, 64); sk += __shfl_xor(sk, off, 64);
        }
        if (lane == 0) { redq[wid] = sq; redk[wid] = sk; }
        __syncthreads();
        const float qn = yq * rsqrtf(redq[0]+redq[1]+EPS_) * SCALE_;
        const float kn = yk * rsqrtf(redk[0]+redk[1]+EPS_);
        ks[tid] = kn; qs[tid] = qn;
        const size_t rab = row * HV_ + h;
        const float av = ain[rab] + dbi;
        const float sp = (av > 20.f) ? av : log1pf(expf(av));
        const float eg = expf(nea * sp);
        const float beta = 1.f/(1.f+expf(-bin[rab]));
        __syncthreads();
        float pred = 0.f;
#pragma unroll
        for (int k4 = 0; k4 < DK_/4; ++k4) {
            const float4 kv = *reinterpret_cast<const float4*>(&ks[k4*4]);
            float s;
            s = Sr[4*k4+0]*eg; Sr[4*k4+0]=s; pred += kv.x*s;
            s = Sr[4*k4+1]*eg; Sr[4*k4+1]=s; pred += kv.y*s;
            s = Sr[4*k4+2]*eg; Sr[4*k4+2]=s; pred += kv.z*s;
            s = Sr[4*k4+3]*eg; Sr[4*k4+3]=s; pred += kv.w*s;
        }
        const float delta = beta * (yv - pred);
        float o = 0.f;
#pragma unroll
        for (int k4 = 0; k4 < DK_/4; ++k4) {
            const float4 kv = *reinterpret_cast<const float4*>(&ks[k4*4]);
            const float4 qv = *reinterpret_cast<const float4*>(&qs[k4*4]);
            float s;
            s = Sr[4*k4+0]+kv.x*delta; Sr[4*k4+0]=s; o += qv.x*s;
            s = Sr[4*k4+1]+kv.y*delta; Sr[4*k4+1]=s; o += qv.y*s;
            s = Sr[4*k4+2]+kv.z*delta; Sr[4*k4+2]=s; o += qv.z*s;
            s = Sr[4*k4+3]+kv.w*delta; Sr[4*k4+3]=s; o += qv.w*s;
        }
        out[rab * DK_ + tid] = o;
    }
}

extern "C" void kernel_launch(void* const* d_in, const int* in_sizes, int n_in,
                              void* d_out, int out_size, void* d_ws, size_t ws_size,
                              hipStream_t stream) {
    const float* xqkv  = (const float*)d_in[0];
    const float* bin   = (const float*)d_in[1];
    const float* ain   = (const float*)d_in[2];
    const float* wconv = (const float*)d_in[3];
    const float* dtb   = (const float*)d_in[4];
    const float* alg   = (const float*)d_in[5];
    float* out = (float*)d_out;

    const size_t Y_BYTES = (size_t)B_ * S_ * QKV_ * 4;         // 134 MB
    const size_t G_BYTES = (size_t)B_ * S_ * HV_ * 8;          // 1 MB (float2)
    const size_t NEEDED  = Y_BYTES + G_BYTES;

    if (ws_size >= NEEDED) {
        float*  Y  = (float*)d_ws;
        float2* GB = (float2*)((char*)d_ws + Y_BYTES);

        preproc_kernel<<<dim3(4, B_ * S_ / 4), 256, 0, stream>>>(xqkv, wconv, Y);
        gating_kernel<<<dim3((B_ * S_ * HV_ + 255) / 256), 256, 0, stream>>>(
            bin, ain, dtb, alg, GB);
        recur_kernel<<<dim3(HV_, B_, 16), 64, 0, stream>>>(Y, GB, out);
    } else {
        gdn_prefill_fallback<<<dim3(HV_, B_), 128, 0, stream>>>(
            xqkv, bin, ain, wconv, dtb, alg, out);
    }
}